// Round 3
// baseline (70.406 us; speedup 1.0000x reference)
//
#include <hip/hip_runtime.h>

// Problem constants (reference: B=128, K=2048, D=512, c=1.0)
#define B_SZ 128
#define K_SZ 2048
#define D_SZ 512

typedef __attribute__((ext_vector_type(8))) short short8;   // 8 bf16 (MFMA A/B frag)
typedef __attribute__((ext_vector_type(4))) float floatx4;  // MFMA acc

// fp32 -> bf16 RNE via compiler-native fptrunc (pairs lower to
// v_cvt_pk_bf16_f32; bit-identical to the manual +0x7fff RNE trick).
static __device__ inline unsigned short f2b(float f) {
  __bf16 h = (__bf16)f;
  return __builtin_bit_cast(unsigned short, h);
}

static __device__ inline short8 cvt8(float4 lo, float4 hi) {
  short8 r;
  r[0] = (short)f2b(lo.x); r[1] = (short)f2b(lo.y);
  r[2] = (short)f2b(lo.z); r[3] = (short)f2b(lo.w);
  r[4] = (short)f2b(hi.x); r[5] = (short)f2b(hi.y);
  r[6] = (short)f2b(hi.z); r[7] = (short)f2b(hi.w);
  return r;
}

// ONE fused kernel, ZERO-LDS-staging design (R2 post-mortem):
// The MFMA A/B fragment layout (row = lane&15, d = (lane>>4)*8 + j) is
// loadable straight from row-major global fp32 as 2x float4 per lane per
// k-step (quads 0-3 cover a contiguous 128B span per row), so the entire
// LDS staging round-trip (24 b128 stores + 24 b128 reads/thread, 2 extra
// barrier drains, 66.6KB LDS -> 2 blocks/CU cap) is pure overhead. Drop it.
//
// Decomposition: block = 32 b x 16 k tile; wave w owns d-QUARTER w (128
// elems, 4 k-steps) and computes BOTH m-halves against one shared p/a
// fragment -> global-load volume and cvt count identical to the staged
// version (32 float4 + 64 cvt_pk / thread, no duplication), 4 accumulators
// (cs0,cs1,ca0,ca1), 16 MFMAs/wave. Per-row stats (vv,uu,<p,a>,aa) are
// accumulated inline from the same fp32 registers, quad-reduced via
// shfl_xor(16,32), combined 4-way (one per wave) in the epilogue.
// ONE __syncthreads() total. LDS 17.7KB -> occupancy no longer LDS-capped.
//
// blockIdx mapping: kt = blk & 127 -> the 4 m-blocks of one k-tile differ by
// 128 ≡ 0 (mod 8) -> same XCD -> p/a rows hit that XCD's L2 after first touch.
// Fragment layouts (m89/m91-verified):
//   A/B: row = lane&15, d = (lane>>4)*8 + j (16B/lane, row-major == B^T)
//   C/D: n = lane&15, m = (lane>>4)*4 + reg
__global__ __launch_bounds__(256) void fused_kernel(
    const float* __restrict__ x, const float* __restrict__ p,
    const float* __restrict__ a, float* __restrict__ out) {
  // part_s0 [1024] | part_s1 | part_a0 | part_a1 | vv[32][4] | pp[16][4] |
  // pa[16][4] | aa[16][4]  = 4416 floats = 17664 B
  __shared__ float lds[4416];

  const int t = threadIdx.x;
  const int mt = blockIdx.x >> 7;   // 0..3   (m-tile of 32 b)
  const int kt = blockIdx.x & 127;  // 0..127 (k-tile of 16 k)
  const int w = t >> 6, lane = t & 63;
  const int row16 = lane & 15, quad = lane >> 4;

  const int dbase = w * 128 + quad * 8;  // this wave's d-quarter, lane's slot
  const float* xb0 = x + (size_t)(mt * 32 + row16) * D_SZ + dbase;  // rows 0-15
  const float* xb1 = xb0 + (size_t)16 * D_SZ;                       // rows 16-31
  const float* pbr = p + (size_t)(kt * 16 + row16) * D_SZ + dbase;
  const float* abr = a + (size_t)(kt * 16 + row16) * D_SZ + dbase;

  floatx4 cs0 = {0.f, 0.f, 0.f, 0.f}, cs1 = {0.f, 0.f, 0.f, 0.f};
  floatx4 ca0 = {0.f, 0.f, 0.f, 0.f}, ca1 = {0.f, 0.f, 0.f, 0.f};
  float vv0 = 0.f, vv1 = 0.f, pp = 0.f, pa = 0.f, aa = 0.f;

#pragma unroll
  for (int dc = 0; dc < 4; ++dc) {  // 4 k-steps of 32 within the quarter
    const int off = dc * 32;
    float4 x00 = *(const float4*)(xb0 + off);
    float4 x01 = *(const float4*)(xb0 + off + 4);
    float4 x10 = *(const float4*)(xb1 + off);
    float4 x11 = *(const float4*)(xb1 + off + 4);
    float4 pv0 = *(const float4*)(pbr + off);
    float4 pv1 = *(const float4*)(pbr + off + 4);
    float4 av0 = *(const float4*)(abr + off);
    float4 av1 = *(const float4*)(abr + off + 4);

    vv0 += x00.x * x00.x + x00.y * x00.y + x00.z * x00.z + x00.w * x00.w +
           x01.x * x01.x + x01.y * x01.y + x01.z * x01.z + x01.w * x01.w;
    vv1 += x10.x * x10.x + x10.y * x10.y + x10.z * x10.z + x10.w * x10.w +
           x11.x * x11.x + x11.y * x11.y + x11.z * x11.z + x11.w * x11.w;
    pp += pv0.x * pv0.x + pv0.y * pv0.y + pv0.z * pv0.z + pv0.w * pv0.w +
          pv1.x * pv1.x + pv1.y * pv1.y + pv1.z * pv1.z + pv1.w * pv1.w;
    pa += pv0.x * av0.x + pv0.y * av0.y + pv0.z * av0.z + pv0.w * av0.w +
          pv1.x * av1.x + pv1.y * av1.y + pv1.z * av1.z + pv1.w * av1.w;
    aa += av0.x * av0.x + av0.y * av0.y + av0.z * av0.z + av0.w * av0.w +
          av1.x * av1.x + av1.y * av1.y + av1.z * av1.z + av1.w * av1.w;

    short8 af0 = cvt8(x00, x01);
    short8 af1 = cvt8(x10, x11);
    short8 bp = cvt8(pv0, pv1);
    short8 bv = cvt8(av0, av1);
    cs0 = __builtin_amdgcn_mfma_f32_16x16x32_bf16(af0, bp, cs0, 0, 0, 0);
    cs1 = __builtin_amdgcn_mfma_f32_16x16x32_bf16(af1, bp, cs1, 0, 0, 0);
    ca0 = __builtin_amdgcn_mfma_f32_16x16x32_bf16(af0, bv, ca0, 0, 0, 0);
    ca1 = __builtin_amdgcn_mfma_f32_16x16x32_bf16(af1, bv, ca1, 0, 0, 0);
  }

  // Quad-reduce stats (lane bits 4,5): all quads end holding the row sum
  // for this wave's d-quarter.
  vv0 += __shfl_xor(vv0, 16, 64); vv0 += __shfl_xor(vv0, 32, 64);
  vv1 += __shfl_xor(vv1, 16, 64); vv1 += __shfl_xor(vv1, 32, 64);
  pp  += __shfl_xor(pp, 16, 64);  pp  += __shfl_xor(pp, 32, 64);
  pa  += __shfl_xor(pa, 16, 64);  pa  += __shfl_xor(pa, 32, 64);
  aa  += __shfl_xor(aa, 16, 64);  aa  += __shfl_xor(aa, 32, 64);

  // Publish partials + stats; ONE barrier.
  float* pS0 = lds;          // [4 waves][64 lanes][4 regs]
  float* pS1 = lds + 1024;
  float* pA0 = lds + 2048;
  float* pA1 = lds + 3072;
  float* vvL = lds + 4096;   // [32][4]
  float* ppL = lds + 4224;   // [16][4]
  float* paL = lds + 4288;   // [16][4]
  float* aaL = lds + 4352;   // [16][4]
  *(floatx4*)&pS0[t * 4] = cs0;  // t == w*64 + lane
  *(floatx4*)&pS1[t * 4] = cs1;
  *(floatx4*)&pA0[t * 4] = ca0;
  *(floatx4*)&pA1[t * 4] = ca1;
  if (quad == 0) { vvL[row16 * 4 + w] = vv0; aaL[row16 * 4 + w] = aa; }
  if (quad == 1) vvL[(16 + row16) * 4 + w] = vv1;
  if (quad == 2) ppL[row16 * 4 + w] = pp;
  if (quad == 3) paL[row16 * 4 + w] = pa;
  __syncthreads();

  // Epilogue: 2 outputs per thread (c = 1).
  const int bm = mt * 32, kn = kt * 16;
#pragma unroll
  for (int o = 0; o < 2; ++o) {
    const int idx = t + o * 256;   // 0..511 -> (m16, n)
    const int m16 = idx >> 4;      // 0..31 local b
    const int n = idx & 15;        // local k
    const int wmI = m16 >> 4, mr = m16 & 15;
    const int lsrc = ((mr >> 2) << 4) | n;
    const int reg = mr & 3;
    const float* S = wmI ? pS1 : pS0;
    const float* A = wmI ? pA1 : pA0;
    const float sdot = S[lsrc * 4 + reg] + S[(64 + lsrc) * 4 + reg] +
                       S[(128 + lsrc) * 4 + reg] + S[(192 + lsrc) * 4 + reg];
    const float adot = A[lsrc * 4 + reg] + A[(64 + lsrc) * 4 + reg] +
                       A[(128 + lsrc) * 4 + reg] + A[(192 + lsrc) * 4 + reg];
    floatx4 v4 = *(const floatx4*)&vvL[m16 * 4];
    floatx4 u4 = *(const floatx4*)&ppL[n * 4];
    floatx4 q4 = *(const floatx4*)&paL[n * 4];
    floatx4 a4 = *(const floatx4*)&aaL[n * 4];
    const float vvb = (v4[0] + v4[1]) + (v4[2] + v4[3]);
    const float uuk = (u4[0] + u4[1]) + (u4[2] + u4[3]);
    const float nuak = -((q4[0] + q4[1]) + (q4[2] + q4[3]));
    const float ank = sqrtf((a4[0] + a4[1]) + (a4[2] + a4[3]));
    const float beta = 1.f - uuk;            // 1 - c*||p||^2
    const float scale = (2.f / beta) * ank;  // lam_p * ||a||
    const float uv = -sdot;                  // <u,x> = -<p,x>
    const float alpha = 1.f + 2.f * uv + vvb;
    const float den = 1.f + 2.f * uv + uuk * vvb;
    const float inv = 1.f / den;
    const float wwn =
        (alpha * alpha * uuk + 2.f * alpha * beta * uv + beta * beta * vvb) *
        inv * inv;
    const float wa = (alpha * nuak + beta * adot) * inv;
    const float z = 2.f * wa / (ank * (1.f - wwn));
    out[(size_t)(bm + m16) * K_SZ + (kn + n)] = scale * asinhf(z);
  }
}

extern "C" void kernel_launch(void* const* d_in, const int* in_sizes, int n_in,
                              void* d_out, int out_size, void* d_ws, size_t ws_size,
                              hipStream_t stream) {
  const float* x = (const float*)d_in[0];  // inp [B,D]
  const float* p = (const float*)d_in[1];  // p   [K,D]
  const float* a = (const float*)d_in[2];  // a   [K,D]
  float* out = (float*)d_out;              // [B,K] fp32
  (void)d_ws; (void)ws_size;               // no workspace needed

  fused_kernel<<<(B_SZ / 32) * (K_SZ / 16), 256, 0, stream>>>(x, p, a, out);
}

// Round 4
// 66.731 us; speedup vs baseline: 1.0551x; 1.0551x over previous
//
#include <hip/hip_runtime.h>

// Problem constants (reference: B=128, K=2048, D=512, c=1.0)
#define B_SZ 128
#define K_SZ 2048
#define D_SZ 512
#define ROWP 520  // padded LDS row stride in bf16 (1040 B = 65 x 16B chunks,
                  // 65 % 8 == 1 -> 16 rows cycle all 8 bank-quads: b128
                  // fragment reads are perfectly bank-balanced)

typedef __attribute__((ext_vector_type(8))) short short8;   // 8 bf16
typedef __attribute__((ext_vector_type(4))) float floatx4;  // MFMA acc

// fp32 -> bf16 RNE via compiler-native fptrunc (pairs lower to
// v_cvt_pk_bf16_f32; bit-identical to the manual +0x7fff RNE trick).
static __device__ inline unsigned short f2b(float f) {
  __bf16 h = (__bf16)f;
  return __builtin_bit_cast(unsigned short, h);
}

// ONE fused kernel: stage x/p/a tiles fp32->bf16 into LDS while computing
// per-row stats (vv, uu, nua, an) in fp32, then dual bf16-MFMA GEMM
// (<x,p>, <x,a>), partial-combine through LDS, fused hyperbolic-MLR epilogue.
// Block = 32 b x 16 k. Grid = 4 x 128 = 512 blocks = 2/CU (LDS 73.3 KB still
// fits exactly 2). 256 threads = 4 waves: wave w -> m-half (w&1), d-half
// (w>>1), each wave does 8 k-steps x 2 MFMAs on a 16x16 tile.
//
// Design ledger (R0-R3):
//  - R1 two-kernel split: -staging redundancy, +1 dispatch -> +3.2us. REVERTED.
//  - R3 zero-LDS fragment-direct loads: scatters each wave-load over 16 rows
//    x 2KB stride (16x64B segments vs 1-2 coalesced 1KB segments) -> +3.7us.
//    REVERTED. LDS staging IS the cheap re-layout path on this problem.
//  - This round: partials get a DEDICATED LDS buffer (was: aliased onto ps),
//    removing the middle __syncthreads() whose only job was alias protection.
//    3 barriers -> 2.
//
// blockIdx mapping: kt = blk & 127 -> the 4 m-blocks of one k-tile differ by
// 128 ≡ 0 (mod 8) -> same XCD -> p/a rows hit that XCD's L2 after first touch.
// Fragment layouts (m89/m91-verified):
//   A/B: row = lane&15, d = (lane>>4)*8 + j (16B/lane, row-major == B^T)
//   C/D: n = lane&15, m = (lane>>4)*4 + reg
__global__ __launch_bounds__(256, 2) void fused_kernel(
    const float* __restrict__ x, const float* __restrict__ p,
    const float* __restrict__ a, float* __restrict__ out) {
  __shared__ unsigned short xs[32 * ROWP];   // 33280 B
  __shared__ unsigned short ps[16 * ROWP];   // 16640 B
  __shared__ unsigned short as_[16 * ROWP];  // 16640 B
  __shared__ float part[2048];               // part_s[1024] | part_a[1024]
  __shared__ float stats[32 + 48];           // vv[32] | uu[16] | nua[16] | an[16]

  const int t = threadIdx.x;
  const int bm = (blockIdx.x >> 7) * 32;   // 4 m-tiles of 32 b
  const int kn = (blockIdx.x & 127) * 16;  // 128 k-tiles of 16 k

  // ---- Phase 0a: stage x (32 rows), vv stats. 8 threads/row, 16 float4 ea.
  {
    const int r = t >> 3, s = t & 7;
    const float4* src = (const float4*)(x + (size_t)(bm + r) * D_SZ);
    float vvp = 0.f;
#pragma unroll
    for (int i = 0; i < 16; ++i) {
      float4 v = src[s + i * 8];
      vvp += v.x * v.x + v.y * v.y + v.z * v.z + v.w * v.w;
      ushort4 c;
      c.x = f2b(v.x); c.y = f2b(v.y); c.z = f2b(v.z); c.w = f2b(v.w);
      *(ushort4*)&xs[r * ROWP + (s + i * 8) * 4] = c;
    }
    vvp += __shfl_xor(vvp, 1, 64);
    vvp += __shfl_xor(vvp, 2, 64);
    vvp += __shfl_xor(vvp, 4, 64);
    if (s == 0) stats[r] = vvp;
  }

  // ---- Phase 0b: stage p,a (16 rows), uu/nua/an stats. 16 thr/row, 8 f4 ea.
  {
    const int r = t >> 4, s = t & 15;
    const float4* sp = (const float4*)(p + (size_t)(kn + r) * D_SZ);
    const float4* sa = (const float4*)(a + (size_t)(kn + r) * D_SZ);
    float pp = 0.f, pa = 0.f, aa = 0.f;
#pragma unroll
    for (int i = 0; i < 8; ++i) {
      float4 pv = sp[s + i * 16];
      float4 av = sa[s + i * 16];
      pp += pv.x * pv.x + pv.y * pv.y + pv.z * pv.z + pv.w * pv.w;
      pa += pv.x * av.x + pv.y * av.y + pv.z * av.z + pv.w * av.w;
      aa += av.x * av.x + av.y * av.y + av.z * av.z + av.w * av.w;
      ushort4 pc, ac;
      pc.x = f2b(pv.x); pc.y = f2b(pv.y); pc.z = f2b(pv.z); pc.w = f2b(pv.w);
      ac.x = f2b(av.x); ac.y = f2b(av.y); ac.z = f2b(av.z); ac.w = f2b(av.w);
      *(ushort4*)&ps[r * ROWP + (s + i * 16) * 4] = pc;
      *(ushort4*)&as_[r * ROWP + (s + i * 16) * 4] = ac;
    }
    pp += __shfl_xor(pp, 1, 64);
    pa += __shfl_xor(pa, 1, 64);
    aa += __shfl_xor(aa, 1, 64);
    pp += __shfl_xor(pp, 2, 64);
    pa += __shfl_xor(pa, 2, 64);
    aa += __shfl_xor(aa, 2, 64);
    pp += __shfl_xor(pp, 4, 64);
    pa += __shfl_xor(pa, 4, 64);
    aa += __shfl_xor(aa, 4, 64);
    pp += __shfl_xor(pp, 8, 64);
    pa += __shfl_xor(pa, 8, 64);
    aa += __shfl_xor(aa, 8, 64);
    if (s == 0) {
      stats[32 + r] = pp;        // uu
      stats[48 + r] = -pa;       // nua
      stats[64 + r] = sqrtf(aa); // an
    }
  }
  __syncthreads();

  // ---- Phase 1: dual MFMA. wave w: m-half wm = w&1, d-half dh = w>>1.
  const int w = t >> 6, lane = t & 63;
  const int row16 = lane & 15, quad = lane >> 4;
  const int wm = w & 1, dh = w >> 1;
  const unsigned short* xrow = &xs[(wm * 16 + row16) * ROWP + dh * 256 + quad * 8];
  const unsigned short* prow = &ps[row16 * ROWP + dh * 256 + quad * 8];
  const unsigned short* arow = &as_[row16 * ROWP + dh * 256 + quad * 8];
  floatx4 cs = {0.f, 0.f, 0.f, 0.f};
  floatx4 ca = {0.f, 0.f, 0.f, 0.f};
#pragma unroll
  for (int dc = 0; dc < 8; ++dc) {
    short8 af = *(const short8*)(xrow + dc * 32);
    short8 bp = *(const short8*)(prow + dc * 32);
    short8 bv = *(const short8*)(arow + dc * 32);
    cs = __builtin_amdgcn_mfma_f32_16x16x32_bf16(af, bp, cs, 0, 0, 0);
    ca = __builtin_amdgcn_mfma_f32_16x16x32_bf16(af, bv, ca, 0, 0, 0);
  }

  // ---- Phase 2: combine d-halves through dedicated LDS (no alias, so no
  // barrier needed between the MFMA reads above and these writes).
  float* part_s = part;                // [4 waves][64 lanes][4 regs] = 4 KB
  float* part_a = part + 1024;         // 4 KB
  *(floatx4*)&part_s[(w * 64 + lane) * 4] = cs;
  *(floatx4*)&part_a[(w * 64 + lane) * 4] = ca;
  __syncthreads();

  // ---- Phase 3: epilogue, 2 outputs per thread (c = 1).
#pragma unroll
  for (int o = 0; o < 2; ++o) {
    const int idx = t + o * 256;   // 0..511 -> (m16, n)
    const int m16 = idx >> 4;      // 0..31 local b
    const int n = idx & 15;        // local k
    const int wmI = m16 >> 4, mr = m16 & 15;
    const int lsrc = ((mr >> 2) << 4) | n;
    const int reg = mr & 3;
    const float sdot = part_s[(wmI * 64 + lsrc) * 4 + reg] +
                       part_s[((2 + wmI) * 64 + lsrc) * 4 + reg];
    const float adot = part_a[(wmI * 64 + lsrc) * 4 + reg] +
                       part_a[((2 + wmI) * 64 + lsrc) * 4 + reg];
    const float vvb = stats[m16];
    const float uuk = stats[32 + n];
    const float nuak = stats[48 + n];
    const float ank = stats[64 + n];
    const float beta = 1.f - uuk;            // 1 - c*||p||^2
    const float scale = (2.f / beta) * ank;  // lam_p * ||a||
    const float uv = -sdot;                  // <u,x> = -<p,x>
    const float alpha = 1.f + 2.f * uv + vvb;
    const float den = 1.f + 2.f * uv + uuk * vvb;
    const float inv = 1.f / den;
    const float wwn =
        (alpha * alpha * uuk + 2.f * alpha * beta * uv + beta * beta * vvb) *
        inv * inv;
    const float wa = (alpha * nuak + beta * adot) * inv;
    const float z = 2.f * wa / (ank * (1.f - wwn));
    out[(size_t)(bm + m16) * K_SZ + (kn + n)] = scale * asinhf(z);
  }
}

extern "C" void kernel_launch(void* const* d_in, const int* in_sizes, int n_in,
                              void* d_out, int out_size, void* d_ws, size_t ws_size,
                              hipStream_t stream) {
  const float* x = (const float*)d_in[0];  // inp [B,D]
  const float* p = (const float*)d_in[1];  // p   [K,D]
  const float* a = (const float*)d_in[2];  // a   [K,D]
  float* out = (float*)d_out;              // [B,K] fp32
  (void)d_ws; (void)ws_size;               // no workspace needed

  fused_kernel<<<(B_SZ / 32) * (K_SZ / 16), 256, 0, stream>>>(x, p, a, out);
}